// Round 17
// baseline (90.309 us; speedup 1.0000x reference)
//
#include <hip/hip_runtime.h>

#define NB 65536
#define NUM_T 200
#define SUB 2            // SUB=8/4/2 all measured absmax == 0.0078125 (bf16
                         // comparison floor); threshold 0.0372

// one RK4 substep on rescaled state (u = beta*S, I); 22 VALU ops
#define SUBSTEP()                                   \
    do {                                            \
        const float bSI1 = u * I;                   \
        const float u2 = fmaf(-cbA, bSI1, u);       \
        const float J1 = fmaf(-cgA, I, I);          \
        const float I2 = fmaf(h2, bSI1, J1);        \
        const float bSI2 = u2 * I2;                 \
        const float u3 = fmaf(-cbA, bSI2, u);       \
        const float J2 = fmaf(-cgA, I2, I);         \
        const float I3 = fmaf(h2, bSI2, J2);        \
        float wb = fmaf(2.0f, bSI2, bSI1);          \
        float wI = fmaf(2.0f, I2, I);               \
        const float bSI3 = u3 * I3;                 \
        const float u4 = fmaf(-cbB, bSI3, u);       \
        const float J3 = fmaf(-cgB, I3, I);         \
        const float I4 = fmaf(h, bSI3, J3);         \
        wb = fmaf(2.0f, bSI3, wb);                  \
        wI = fmaf(2.0f, I3, wI);                    \
        const float bSI4 = u4 * I4;                 \
        wb += bSI4;                                 \
        wI += I4;                                   \
        u = fmaf(-cbF, wb, u);                      \
        const float tt = fmaf(-cgF, wI, I);         \
        I = fmaf(h6, wb, tt);                       \
    } while (0)

// advance one output step (i>0), per-step dt from the fp32 linspace chain
#define STEP(iexpr)                                                     \
    do {                                                                \
        const float tcur = step * (float)(iexpr);                       \
        const float dt   = tcur - tprev;                                \
        tprev = tcur;                                                   \
        const float h  = dt * (1.0f / SUB);                             \
        const float h2 = 0.5f * h;                                      \
        const float h6 = h * (1.0f / 6.0f);                             \
        const float cbA = h2 * beta,  cbB = h * beta,  cbF = h6 * beta; \
        const float cgA = h2 * gamma, cgB = h * gamma, cgF = h6 * gamma;\
        for (int s = 0; s < SUB; ++s) SUBSTEP();                        \
    } while (0)

// emit one 4-step group (12 floats) into this thread's LDS row, swizzled
#define EMIT_GROUP(Q4, IBASE)                                           \
    do {                                                                \
        float c[12];                                                    \
        _Pragma("unroll")                                               \
        for (int j = 0; j < 4; ++j) {                                   \
            const int i = (IBASE) + j;                                  \
            if (i > 0) STEP(i);                                         \
            const float Sout = bpos ? (u * rbeta) : S0;                 \
            c[j * 3 + 0] = Sout;                                        \
            c[j * 3 + 1] = I;                                           \
            c[j * 3 + 2] = 1.0f - Sout - I;                             \
        }                                                               \
        _Pragma("unroll")                                               \
        for (int cc = 0; cc < 3; ++cc) {                                \
            const int phys = ((Q4) * 3 + cc) ^ sw;                      \
            ldsrow4[phys] = make_float4(c[cc * 4], c[cc * 4 + 1],       \
                                        c[cc * 4 + 2], c[cc * 4 + 3]);  \
        }                                                               \
    } while (0)

// compute one 32-step stage into this thread's LDS row
#define EMIT_STAGE(S)                                                   \
    do {                                                                \
        _Pragma("unroll 1")                                             \
        for (int q4 = 0; q4 < 8; ++q4) EMIT_GROUP(q4, (S) * 32 + q4 * 4);\
    } while (0)

#define LGKM0() asm volatile("s_waitcnt lgkmcnt(0)" ::: "memory")

// batch-read the wave's 24 chunks (swizzled) into register bank DV
#define READ24(DV)                                                      \
    do {                                                                \
        _Pragma("unroll")                                               \
        for (int k = 0; k < 24; ++k) {                                  \
            const int id = k * 64 + lane;                               \
            const int r  = id / 24;                                     \
            const int j  = id - r * 24;                                 \
            DV[k] = ldsw4[r * 24 + (j ^ (r & 7))];                      \
        }                                                               \
    } while (0)

// store bank DV to stage-S slice of global (contiguous 384-B runs per instr)
#define STORE24(DV, S)                                                  \
    do {                                                                \
        _Pragma("unroll")                                               \
        for (int k = 0; k < 24; ++k) {                                  \
            const int id = k * 64 + lane;                               \
            const int r  = id / 24;                                     \
            const int j  = id - r * 24;                                 \
            out4[r * 150 + (S) * 24 + j] = DV[k];                       \
        }                                                               \
    } while (0)

__global__ __launch_bounds__(256, 1) void sir_rk4_pipe2_kernel(
    const float4* __restrict__ params, float* __restrict__ out)
{
    // 256 rows x 24 float4 chunks = 98304 B; wave w owns rows [w*64, w*64+64)
    __shared__ float4 lds4[256 * 24];

    const int tid  = threadIdx.x;
    const int lane = tid & 63;
    const int w    = tid >> 6;
    const int blk  = blockIdx.x;
    const int sw   = lane & 7;          // XOR bank swizzle key

    const float4 p = params[blk * 256 + tid];
    const float beta  = p.x;
    const float gamma = p.y;
    const float S0    = p.z;

    float u = beta * S0;                // rescaled state u = beta*S
    float I = p.w;

    const bool  bpos  = (beta > 0.0f);
    const float rbeta = bpos ? (1.0f / beta) : 0.0f;

    const float step = 100.0f / 199.0f; // fp32 linspace step
    float tprev = 0.0f;

    float4* ldsrow4 = lds4 + tid * 24;            // this thread's row
    const float4* ldsw4 = lds4 + (w * 64) * 24;   // wave slice base
    float4* out4 = reinterpret_cast<float4*>(out)
                 + (size_t)(blk * 256 + w * 64) * 150;  // 150 float4 per row

    float4 dvA[24], dvB[24];

    // depth-2 store pipeline: READ(s) precedes STORE(s-1), so dvA/dvB live
    // ranges overlap -> distinct physregs -> the vmcnt wait for STORE(s)
    // lands at READ(s+2), giving stores a full stage of compute to drain.
    EMIT_STAGE(0); LGKM0(); READ24(dvA);
    EMIT_STAGE(1); LGKM0(); READ24(dvB); STORE24(dvA, 0);
    EMIT_STAGE(2); LGKM0(); READ24(dvA); STORE24(dvB, 1);
    EMIT_STAGE(3); LGKM0(); READ24(dvB); STORE24(dvA, 2);
    EMIT_STAGE(4); LGKM0(); READ24(dvA); STORE24(dvB, 3);
    EMIT_STAGE(5); LGKM0(); READ24(dvB); STORE24(dvA, 4);

    // tail: 8 steps (192..199) = 6 chunks/row
    {
        #pragma unroll 1
        for (int q4 = 0; q4 < 2; ++q4) EMIT_GROUP(q4, 192 + q4 * 4);
        LGKM0();
        float4 dvT[6];
        #pragma unroll
        for (int k = 0; k < 6; ++k) {
            const int id = k * 64 + lane;
            const int r  = id / 6;
            const int j  = id - r * 6;
            dvT[k] = ldsw4[r * 24 + (j ^ (r & 7))];
        }
        STORE24(dvB, 5);
        #pragma unroll
        for (int k = 0; k < 6; ++k) {
            const int id = k * 64 + lane;
            const int r  = id / 6;
            const int j  = id - r * 6;
            out4[r * 150 + 144 + j] = dvT[k];
        }
    }
}

extern "C" void kernel_launch(void* const* d_in, const int* in_sizes, int n_in,
                              void* d_out, int out_size, void* d_ws, size_t ws_size,
                              hipStream_t stream) {
    (void)in_sizes; (void)n_in; (void)out_size; (void)d_ws; (void)ws_size;
    const float4* params = (const float4*)d_in[0];
    float* out = (float*)d_out;
    sir_rk4_pipe2_kernel<<<NB / 256, 256, 0, stream>>>(params, out);
}

// Round 18
// 42.135 us; speedup vs baseline: 2.1433x; 2.1433x over previous
//
#include <hip/hip_runtime.h>

#define NB 65536
#define NUM_T 200
#define SUB 2            // SUB=8/4/2 all measured absmax == 0.0078125 (bf16
                         // comparison floor); threshold 0.0372

// one RK4 substep on rescaled state (u = beta*S, I); 22 VALU ops
#define SUBSTEP()                                   \
    do {                                            \
        const float bSI1 = u * I;                   \
        const float u2 = fmaf(-cbA, bSI1, u);       \
        const float J1 = fmaf(-cgA, I, I);          \
        const float I2 = fmaf(h2, bSI1, J1);        \
        const float bSI2 = u2 * I2;                 \
        const float u3 = fmaf(-cbA, bSI2, u);       \
        const float J2 = fmaf(-cgA, I2, I);         \
        const float I3 = fmaf(h2, bSI2, J2);        \
        float wb = fmaf(2.0f, bSI2, bSI1);          \
        float wI = fmaf(2.0f, I2, I);               \
        const float bSI3 = u3 * I3;                 \
        const float u4 = fmaf(-cbB, bSI3, u);       \
        const float J3 = fmaf(-cgB, I3, I);         \
        const float I4 = fmaf(h, bSI3, J3);         \
        wb = fmaf(2.0f, bSI3, wb);                  \
        wI = fmaf(2.0f, I3, wI);                    \
        const float bSI4 = u4 * I4;                 \
        wb += bSI4;                                 \
        wI += I4;                                   \
        u = fmaf(-cbF, wb, u);                      \
        const float tt = fmaf(-cgF, wI, I);         \
        I = fmaf(h6, wb, tt);                       \
    } while (0)

// advance one output step (i>0), per-step dt from the fp32 linspace chain
#define STEP(iexpr)                                                     \
    do {                                                                \
        const float tcur = step * (float)(iexpr);                       \
        const float dt   = tcur - tprev;                                \
        tprev = tcur;                                                   \
        const float h  = dt * (1.0f / SUB);                             \
        const float h2 = 0.5f * h;                                      \
        const float h6 = h * (1.0f / 6.0f);                             \
        const float cbA = h2 * beta,  cbB = h * beta,  cbF = h6 * beta; \
        const float cgA = h2 * gamma, cgB = h * gamma, cgF = h6 * gamma;\
        for (int s = 0; s < SUB; ++s) SUBSTEP();                        \
    } while (0)

// Emit groups [G0,G1) of a 32-step stage into the circular 30-slot LDS row.
// Chunk jj = g*3+cc = row bytes [16jj+384s, +16) -> slot (OS+jj) mod 30.
// SAVE=1 (stage 0 head): also save chunks 0..5 = row head bytes [0,96).
#define EMIT_GROUPS(SBASE, OS, G0, G1, SAVE)                            \
    do {                                                                \
        _Pragma("unroll 1")                                             \
        for (int g = (G0); g < (G1); ++g) {                             \
            float c[12];                                                \
            _Pragma("unroll")                                           \
            for (int j = 0; j < 4; ++j) {                               \
                const int i = (SBASE) + g * 4 + j;                      \
                if (i > 0) STEP(i);                                     \
                const float Sout = bpos ? (u * rbeta) : S0;             \
                c[j * 3 + 0] = Sout;                                    \
                c[j * 3 + 1] = I;                                       \
                c[j * 3 + 2] = 1.0f - Sout - I;                         \
            }                                                           \
            _Pragma("unroll")                                           \
            for (int cc = 0; cc < 3; ++cc) {                            \
                int slot = (OS) + g * 3 + cc;                           \
                if (slot >= 30) slot -= 30;                             \
                const float4 v = make_float4(c[cc * 4], c[cc * 4 + 1],  \
                                             c[cc * 4 + 2], c[cc * 4 + 3]); \
                myrow[slot ^ key] = v;                                  \
                if (SAVE) mside[g * 3 + cc] = v;                        \
            }                                                           \
        }                                                               \
    } while (0)

#define LGKM0() asm volatile("s_waitcnt lgkmcnt(0)" ::: "memory")

// Drain window w (OW = (24w)%30, W24 = 24w): per row, 24 float4 = 3 full
// 128-B lines at flat bytes [r*2400 + 384w + 32(r&3), +384) -- line-aligned.
#define DRAIN(OW, W24)                                                  \
    do {                                                                \
        float4 dv[24];                                                  \
        _Pragma("unroll")                                               \
        for (int k = 0; k < 24; ++k) {                                  \
            const int id = k * 64 + lane;                               \
            const int r  = id / 24;                                     \
            const int j  = id - r * 24;                                 \
            int slot = (OW) + 2 * (r & 3) + j;                          \
            if (slot >= 30) slot -= 30;                                 \
            dv[k] = ldsw[(r << 5) + (slot ^ (r & 7))];                  \
        }                                                               \
        _Pragma("unroll")                                               \
        for (int k = 0; k < 24; ++k) {                                  \
            const int id = k * 64 + lane;                               \
            const int r  = id / 24;                                     \
            const int j  = id - r * 24;                                 \
            out4[r * 150 + (W24) + 2 * (r & 3) + j] = dv[k];            \
        }                                                               \
    } while (0)

__global__ __launch_bounds__(256, 1) void sir_rk4_la_kernel(
    const float4* __restrict__ params, float* __restrict__ out)
{
    // circular rows: 30 slots used + 2 pad (XOR swizzle needs pow2 capacity)
    __shared__ float4 lds4[256 * 32];   // 131072 B
    __shared__ float4 side[256 * 6];    // 24576 B: per-row head bytes [0,96)

    const int tid  = threadIdx.x;       // row within block
    const int lane = tid & 63;
    const int wv   = tid >> 6;
    const int blk  = blockIdx.x;
    const int key  = tid & 7;           // XOR bank swizzle (own row)

    const float4 p = params[blk * 256 + tid];
    const float beta  = p.x;
    const float gamma = p.y;
    const float S0    = p.z;

    float u = beta * S0;                // rescaled state u = beta*S
    float I = p.w;

    const bool  bpos  = (beta > 0.0f);
    const float rbeta = bpos ? (1.0f / beta) : 0.0f;

    const float step = 100.0f / 199.0f; // fp32 linspace step
    float tprev = 0.0f;

    float4* myrow = &lds4[tid * 32];
    float4* mside = &side[tid * 6];
    const float4* ldsw  = &lds4[(wv * 64) * 32];   // wave slice (64 rows)
    const float4* sidew = &side[(wv * 64) * 6];
    float4* out4 = reinterpret_cast<float4*>(out)
                 + (size_t)(blk * 256 + wv * 64) * 150;   // 150 float4/row

    // stage s: head (8 steps) ; drain window s-1 ; body (24 steps)
    // OS(s) = (24s) % 30: 0,24,18,12,6,0 ; tail OS = 24
    EMIT_GROUPS(0, 0, 0, 2, 1);                      // stage0 head + side save
    EMIT_GROUPS(0, 0, 2, 8, 0);                      // stage0 body

    EMIT_GROUPS(32, 24, 0, 2, 0); LGKM0(); DRAIN(0, 0);     // w=0
    EMIT_GROUPS(32, 24, 2, 8, 0);

    EMIT_GROUPS(64, 18, 0, 2, 0); LGKM0(); DRAIN(24, 24);   // w=1
    EMIT_GROUPS(64, 18, 2, 8, 0);

    EMIT_GROUPS(96, 12, 0, 2, 0); LGKM0(); DRAIN(18, 48);   // w=2
    EMIT_GROUPS(96, 12, 2, 8, 0);

    EMIT_GROUPS(128, 6, 0, 2, 0); LGKM0(); DRAIN(12, 72);   // w=3
    EMIT_GROUPS(128, 6, 2, 8, 0);

    EMIT_GROUPS(160, 0, 0, 2, 0); LGKM0(); DRAIN(6, 96);    // w=4
    EMIT_GROUPS(160, 0, 2, 8, 0);

    EMIT_GROUPS(192, 24, 0, 2, 0);                   // tail 8 steps -> slots 24..29
    LGKM0();
    DRAIN(0, 120);                                   // w=5

    // boundary straddler lines: row rA tail (6-2cA float4) + row rB head
    // (2cA+2 float4) = one full 128-B line; 48 per wave (cA in {0,1,2})
    if (lane < 48) {
        const int g3 = lane / 3;
        const int cA = lane - g3 * 3;
        const int rA = g3 * 4 + cA;
        const int rB = rA + 1;
        const int nA = 6 - 2 * cA;
        const int gbase = rA * 150 + 144 + 2 * cA;
        #pragma unroll
        for (int t = 0; t < 8; ++t) {
            float4 v;
            if (t < nA) {
                const int slot = 24 + 2 * cA + t;    // row rA tail chunk
                v = ldsw[(rA << 5) + (slot ^ (rA & 7))];
            } else {
                v = sidew[rB * 6 + (t - nA)];        // row rB head bytes
            }
            out4[gbase + t] = v;
        }
    }
}

extern "C" void kernel_launch(void* const* d_in, const int* in_sizes, int n_in,
                              void* d_out, int out_size, void* d_ws, size_t ws_size,
                              hipStream_t stream) {
    (void)in_sizes; (void)n_in; (void)out_size; (void)d_ws; (void)ws_size;
    const float4* params = (const float4*)d_in[0];
    float* out = (float*)d_out;
    sir_rk4_la_kernel<<<NB / 256, 256, 0, stream>>>(params, out);
}